// Round 9
// baseline (290.696 us; speedup 1.0000x reference)
//
#include <hip/hip_runtime.h>
#include <math.h>

#define NN 10000
#define EE 320000
#define ET (EE + NN)   // 330000 edges incl. self-loops
#define HBROWS 10048   // hb padded to grid rows (157*64)

typedef __attribute__((ext_vector_type(8))) short short8;          // 8 x bf16
typedef __attribute__((ext_vector_type(8))) unsigned short ushort8_t;
typedef __attribute__((ext_vector_type(4))) float f32x4;
typedef unsigned short u16;

static __device__ __forceinline__ float b2f(u16 u) {
  return __uint_as_float(((unsigned)u) << 16);
}
static __device__ __forceinline__ u16 f2b(float f) {
  unsigned u = __float_as_uint(f);
  unsigned r = (u + 0x7FFFu + ((u >> 16) & 1u)) >> 16;  // RNE
  return (u16)r;
}

// ---------------------------------------------------------------- casts + degree count
__global__ __launch_bounds__(256) void k_castcnt(
    const int* __restrict__ ei, int* __restrict__ cnt, const float* __restrict__ x,
    const float* __restrict__ W0, const float* __restrict__ W1,
    const float* __restrict__ W2, u16* __restrict__ abf, u16* __restrict__ Wt0,
    u16* __restrict__ Wt1, u16* __restrict__ Wt2) {
  int b = blockIdx.x, tid = threadIdx.x;
  if (b < 1250) {
    int e = b * 256 + tid;  // < 320000 == EE == NN*128/4
    atomicAdd(&cnt[ei[EE + e]], 1);
    float4 f = ((const float4*)x)[e];
    ushort4 o;
    o.x = f2b(f.x); o.y = f2b(f.y); o.z = f2b(f.z); o.w = f2b(f.w);
    ((ushort4*)abf)[e] = o;
    return;
  }
  __shared__ float tile[64][65];
  int wt = b - 1250;
  const float* W; u16* Wt; int K, kt, nt_;
  if (wt < 8)       { W = W0; Wt = Wt0; K = 128; kt = wt & 1; nt_ = wt >> 1; }
  else if (wt < 24) { W = W1; Wt = Wt1; K = 256; int u = wt - 8;  kt = u & 3; nt_ = u >> 2; }
  else              { W = W2; Wt = Wt2; K = 256; int u = wt - 24; kt = u & 3; nt_ = u >> 2; }
  int k0 = kt * 64, n0 = nt_ * 64;
  int tx = tid & 63, ty = tid >> 6;
#pragma unroll
  for (int it = 0; it < 16; it++) {
    int row = it * 4 + ty;
    tile[row][tx] = W[(size_t)(k0 + row) * 256 + n0 + tx];
  }
  __syncthreads();
#pragma unroll
  for (int it = 0; it < 16; it++) {
    int row = it * 4 + ty;
    Wt[(size_t)(n0 + row) * K + k0 + tx] = f2b(tile[tx][row]);
  }
}

// ---------------------------------------------------------------- CSR scan
__global__ __launch_bounds__(1024) void k_scan(const int* __restrict__ cnt,
                                               int* __restrict__ rowst,
                                               int* __restrict__ cursor,
                                               int* __restrict__ csrc) {
  __shared__ int ws[16];
  int tid = threadIdx.x, lane = tid & 63, wv = tid >> 6;
  int base = tid * 10;
  int v[10];
  int tot = 0;
#pragma unroll
  for (int i = 0; i < 10; i++) {
    int idx = base + i;
    v[i] = (idx < NN) ? (cnt[idx] + 1) : 0;
    tot += v[i];
  }
  int sc = tot;
#pragma unroll
  for (int off = 1; off < 64; off <<= 1) {
    int t = __shfl_up(sc, off);
    if (lane >= off) sc += t;
  }
  if (lane == 63) ws[wv] = sc;
  __syncthreads();
  if (wv == 0 && lane < 16) {
    int val = ws[lane];
    int s = val;
#pragma unroll
    for (int off = 1; off < 16; off <<= 1) {
      int t = __shfl_up(s, off);
      if (lane >= off) s += t;
    }
    ws[lane] = s - val;
  }
  __syncthreads();
  int run = ws[wv] + sc - tot;
#pragma unroll
  for (int i = 0; i < 10; i++) {
    int idx = base + i;
    if (idx < NN) {
      rowst[idx] = run;
      csrc[run] = idx;        // self-loop at slot 0
      cursor[idx] = run + 1;
      run += v[i];
    }
  }
  if (tid == 1023) rowst[NN] = run;
}

// ---------------------------------------------------------------- MFMA GEMM (+BN in, +dots, +opt fill)
template <int KK, int BN, int FILL>
__global__ __launch_bounds__(256) void k_gemm(
    const u16* __restrict__ A, const float* __restrict__ bkt,
    const float* __restrict__ gam, const float* __restrict__ bet,
    const u16* __restrict__ Wt, const float* __restrict__ as,
    const float* __restrict__ ad, u16* __restrict__ hb,
    float* __restrict__ asrc, float* __restrict__ adst, int H,
    const int* __restrict__ ei, int* __restrict__ cursor, int* __restrict__ csrc) {
  if (FILL && blockIdx.x >= 314) {
    int e = (blockIdx.x - 314) * 256 + threadIdx.x;
    if (e < EE) {
      int d = ei[EE + e];
      int pos = atomicAdd(&cursor[d], 1);
      csrc[pos] = ei[e];
    }
    return;
  }
  __shared__ float2 bnp[256];
  __shared__ u16 lds_c[4][16][136];
  if (BN) {
    int t = threadIdx.x;
    float s = 0.f, q = 0.f;
#pragma unroll 8
    for (int b = 0; b < 32; b++) {
      s += bkt[b * 512 + t];
      q += bkt[b * 512 + 256 + t];
    }
    float m = s * (1.0f / NN);
    float v = q * (1.0f / NN) - m * m;
    float rs = rsqrtf(v + 1e-5f) * gam[t];
    bnp[t] = make_float2(rs, bet[t] - m * rs);
    __syncthreads();
  }
  int wv = threadIdx.x >> 6, lane = threadIdx.x & 63;
  int gx = blockIdx.x >> 1, gy = blockIdx.x & 1;
  int row0 = gx * 64 + wv * 16;
  int col0 = gy * 128;
  int r = lane & 15, g = lane >> 4;
  f32x4 acc[8];
#pragma unroll
  for (int nt = 0; nt < 8; nt++) acc[nt] = (f32x4){0.f, 0.f, 0.f, 0.f};

  int ar = row0 + r;
  if (ar > NN - 1) ar = NN - 1;  // clamp A reads

#pragma unroll
  for (int ks = 0; ks < KK / 32; ks++) {
    short8 af;
    short8 raw = *(const short8*)(A + (size_t)ar * KK + ks * 32 + g * 8);
    if (BN == 0) {
      af = raw;
    } else {
      int c0 = ks * 32 + g * 8;
#pragma unroll
      for (int j = 0; j < 8; j++) {
        float2 p = bnp[c0 + j];
        float t = fmaxf(fmaf(b2f((u16)raw[j]), p.x, p.y), 0.f);
        af[j] = (short)f2b(t);
      }
    }
#pragma unroll
    for (int nt = 0; nt < 8; nt++) {
      short8 bf = *(const short8*)(Wt + (size_t)(col0 + nt * 16 + r) * KK + ks * 32 + g * 8);
      acc[nt] = __builtin_amdgcn_mfma_f32_16x16x32_bf16(af, bf, acc[nt], 0, 0, 0);
    }
  }
  // ---- C-store: wave-local LDS transpose -> coalesced ushort8 stores
  // C/D: col = lane&15, row = (lane>>4)*4 + reg   [m89/m91]
#pragma unroll
  for (int nt = 0; nt < 8; nt++)
#pragma unroll
    for (int q = 0; q < 4; q++)
      lds_c[wv][g * 4 + q][nt * 16 + r] = f2b(acc[nt][q]);
#pragma unroll
  for (int j = 0; j < 4; j++) {
    int c = j * 64 + lane;
    int row = c >> 4, off = (c & 15) * 8;
    ushort8_t vv = *(const ushort8_t*)&lds_c[wv][row][off];
    *(ushort8_t*)&hb[(size_t)(row0 + row) * 256 + col0 + off] = vv;
  }
  // ---- attention-dot epilogue (f32 acc)
  float asv[8], adv[8];
#pragma unroll
  for (int nt = 0; nt < 8; nt++) {
    asv[nt] = as[col0 + nt * 16 + r];
    adv[nt] = ad[col0 + nt * 16 + r];
  }
#pragma unroll
  for (int q = 0; q < 4; q++) {
    int row = row0 + g * 4 + q;
    if (H == 4) {
#pragma unroll
      for (int hh = 0; hh < 2; hh++) {
        float ps = 0.f, pd = 0.f;
#pragma unroll
        for (int k = 0; k < 4; k++) {
          ps = fmaf(acc[hh * 4 + k][q], asv[hh * 4 + k], ps);
          pd = fmaf(acc[hh * 4 + k][q], adv[hh * 4 + k], pd);
        }
#pragma unroll
        for (int off = 1; off < 16; off <<= 1) {
          ps += __shfl_xor(ps, off);
          pd += __shfl_xor(pd, off);
        }
        if (r == 0 && row < NN) {
          int slot = 2 * gy + hh;
          asrc[row * 4 + slot] = ps;
          adst[row * 4 + slot] = pd;
        }
      }
    } else {
      float ps = 0.f, pd = 0.f;
#pragma unroll
      for (int nt = 0; nt < 8; nt++) {
        ps = fmaf(acc[nt][q], asv[nt], ps);
        pd = fmaf(acc[nt][q], adv[nt], pd);
      }
#pragma unroll
      for (int off = 1; off < 16; off <<= 1) {
        ps += __shfl_xor(ps, off);
        pd += __shfl_xor(pd, off);
      }
      if (r == 0 && row < NN) {
        int slot = 2 * gy;
        asrc[row * 4 + slot] = ps;
        asrc[row * 4 + slot + 1] = 0.f;
        adst[row * 4 + slot] = pd;
        adst[row * 4 + slot + 1] = 0.f;
      }
    }
  }
}

// ---------------------------------------------------------------- fused softmax+agg (+BN partials)
// Phase A: wave softmax (lane-per-edge, ids+weights to LDS, zero-pad to x32).
// Phase B: TWO channel-half passes (per-pass gather footprint 2.56MB -> L2-
// resident); lane = (edge-quad q, channel-hex cl16); 32 edges/iter = 8
// independent 16B gathers per lane; combine via shfl_xor(16/32).
template <int H, int BOUT>
__global__ __launch_bounds__(256) void k_softagg(
    const int* __restrict__ rowst, const int* __restrict__ csrc,
    const float* __restrict__ asrc, const float* __restrict__ adst,
    const u16* __restrict__ hb, const float* __restrict__ bias,
    float* __restrict__ outf, u16* __restrict__ outb, float* __restrict__ bkt) {
  __shared__ int lds_s[4][128];
  __shared__ float lds_w[4][128][H];
  __shared__ float lds_v[4][256];
  __shared__ float lds_q[4][256];
  int wv = threadIdx.x >> 6, lane = threadIdx.x & 63;
  int n = blockIdx.x * 4 + wv;  // NN % 4 == 0
  int rs = rowst[n], re = rowst[n + 1];

  float ad[H];
  {
    float4 t = ((const float4*)adst)[n];
    if (H == 4) { ad[0] = t.x; ad[1] = t.y; ad[2] = t.z; ad[3] = t.w; }
    else ad[0] = t.x + t.y + t.z + t.w;
  }
  float mx[H], sm[H];
#pragma unroll
  for (int h = 0; h < H; h++) { mx[h] = -1e30f; sm[h] = 0.f; }

  int e0 = rs + lane, e1 = e0 + 64;
  bool h0 = e0 < re, h1 = e1 < re;
  float a0[H], a1[H];

  if (h0) {
    int s = csrc[e0];
    lds_s[wv][lane] = s;
    float4 t = ((const float4*)asrc)[s];
    if (H == 4) { a0[0] = t.x; a0[1] = t.y; a0[2] = t.z; a0[3] = t.w; }
    else a0[0] = t.x + t.y + t.z + t.w;
#pragma unroll
    for (int h = 0; h < H; h++) {
      float v = a0[h] + ad[h];
      v = v > 0.f ? v : 0.2f * v;
      a0[h] = v;
      mx[h] = fmaxf(mx[h], v);
    }
  }
  if (h1) {
    int s = csrc[e1];
    lds_s[wv][64 + lane] = s;
    float4 t = ((const float4*)asrc)[s];
    if (H == 4) { a1[0] = t.x; a1[1] = t.y; a1[2] = t.z; a1[3] = t.w; }
    else a1[0] = t.x + t.y + t.z + t.w;
#pragma unroll
    for (int h = 0; h < H; h++) {
      float v = a1[h] + ad[h];
      v = v > 0.f ? v : 0.2f * v;
      a1[h] = v;
      mx[h] = fmaxf(mx[h], v);
    }
  }
  for (int e = rs + 128 + lane; e < re; e += 64) {  // cold (deg>128): max only
    int s = csrc[e];
    float4 t = ((const float4*)asrc)[s];
    float a[H];
    if (H == 4) { a[0] = t.x; a[1] = t.y; a[2] = t.z; a[3] = t.w; }
    else a[0] = t.x + t.y + t.z + t.w;
#pragma unroll
    for (int h = 0; h < H; h++) {
      float v = a[h] + ad[h];
      v = v > 0.f ? v : 0.2f * v;
      mx[h] = fmaxf(mx[h], v);
    }
  }
#pragma unroll
  for (int off = 32; off; off >>= 1)
#pragma unroll
    for (int h = 0; h < H; h++) mx[h] = fmaxf(mx[h], __shfl_xor(mx[h], off));

  if (h0) {
#pragma unroll
    for (int h = 0; h < H; h++) {
      a0[h] = __expf(a0[h] - mx[h]);
      sm[h] += a0[h];
      lds_w[wv][lane][h] = a0[h];
    }
  }
  if (h1) {
#pragma unroll
    for (int h = 0; h < H; h++) {
      a1[h] = __expf(a1[h] - mx[h]);
      sm[h] += a1[h];
      lds_w[wv][64 + lane][h] = a1[h];
    }
  }
  for (int e = rs + 128 + lane; e < re; e += 64) {  // cold: exp+sum
    int s = csrc[e];
    float4 t = ((const float4*)asrc)[s];
    float a[H];
    if (H == 4) { a[0] = t.x; a[1] = t.y; a[2] = t.z; a[3] = t.w; }
    else a[0] = t.x + t.y + t.z + t.w;
#pragma unroll
    for (int h = 0; h < H; h++) {
      float v = a[h] + ad[h];
      v = v > 0.f ? v : 0.2f * v;
      sm[h] += __expf(v - mx[h]);
    }
  }
#pragma unroll
  for (int off = 32; off; off >>= 1)
#pragma unroll
    for (int h = 0; h < H; h++) sm[h] += __shfl_xor(sm[h], off);

  float inv[H];
#pragma unroll
  for (int h = 0; h < H; h++) inv[h] = 1.0f / (sm[h] + 1e-16f);

  // ---- zero-pad LDS slots up to a multiple of 32
  int m = re - rs;
  if (m > 128) m = 128;
  int mp = (m + 31) & ~31;
  if (mp > 128) mp = 128;
  for (int p = m + lane; p < mp; p += 64) {
    lds_s[wv][p] = n;  // valid row; weight 0
#pragma unroll
    for (int h = 0; h < H; h++) lds_w[wv][p][h] = 0.f;
  }

  // ---- phase B: two channel-half passes
  int q = lane >> 4, cl16 = lane & 15;
  const ushort8_t* h8 = (const ushort8_t*)hb;
#pragma unroll
  for (int p = 0; p < 2; p++) {
    int cbase = p * 128 + cl16 * 8;  // this lane's channel base
    int head8 = (H == 4) ? (p * 2 + (cl16 >> 3)) : 0;
    float invh = (H == 4) ? (head8 == 0 ? inv[0] : head8 == 1 ? inv[1]
                           : head8 == 2 ? inv[2] : inv[3])
                          : inv[0];
    float mh = (H == 4) ? (head8 == 0 ? mx[0] : head8 == 1 ? mx[1]
                         : head8 == 2 ? mx[2] : mx[3])
                        : mx[0];
    float adh = (H == 4) ? (head8 == 0 ? ad[0] : head8 == 1 ? ad[1]
                          : head8 == 2 ? ad[2] : ad[3])
                         : ad[0];
    float acc[8] = {0.f, 0.f, 0.f, 0.f, 0.f, 0.f, 0.f, 0.f};
    for (int e = 0; e < mp; e += 32) {
      int ss[8];
      float ww[8];
      ushort8_t vv[8];
#pragma unroll
      for (int j = 0; j < 8; j++) ss[j] = lds_s[wv][e + 4 * j + q];
#pragma unroll
      for (int j = 0; j < 8; j++) ww[j] = lds_w[wv][e + 4 * j + q][head8];
#pragma unroll
      for (int j = 0; j < 8; j++) vv[j] = h8[(size_t)ss[j] * 32 + p * 16 + cl16];
#pragma unroll
      for (int j = 0; j < 8; j++)
#pragma unroll
        for (int k = 0; k < 8; k++)
          acc[k] = fmaf(ww[j], b2f((u16)vv[j][k]), acc[k]);
    }
    for (int ee = rs + 128 + q; ee < re; ee += 4) {  // cold: recompute w
      int s = csrc[ee];
      float4 t = ((const float4*)asrc)[s];
      float av = (H == 4) ? (head8 == 0 ? t.x : head8 == 1 ? t.y
                           : head8 == 2 ? t.z : t.w)
                          : (t.x + t.y + t.z + t.w);
      float vv2 = av + adh;
      vv2 = vv2 > 0.f ? vv2 : 0.2f * vv2;
      float w = __expf(vv2 - mh);
      ushort8_t v = h8[(size_t)s * 32 + p * 16 + cl16];
#pragma unroll
      for (int k = 0; k < 8; k++) acc[k] = fmaf(w, b2f((u16)v[k]), acc[k]);
    }
#pragma unroll
    for (int k = 0; k < 8; k++) {
      acc[k] += __shfl_xor(acc[k], 16);
      acc[k] += __shfl_xor(acc[k], 32);
    }
    if (q == 0) {
      float4 ba = ((const float4*)bias)[cbase >> 2];
      float4 bb = ((const float4*)bias)[(cbase >> 2) + 1];
      float r8[8];
      r8[0] = acc[0] * invh + ba.x; r8[1] = acc[1] * invh + ba.y;
      r8[2] = acc[2] * invh + ba.z; r8[3] = acc[3] * invh + ba.w;
      r8[4] = acc[4] * invh + bb.x; r8[5] = acc[5] * invh + bb.y;
      r8[6] = acc[6] * invh + bb.z; r8[7] = acc[7] * invh + bb.w;
      if (BOUT) {
        ushort8_t o;
#pragma unroll
        for (int k = 0; k < 8; k++) o[k] = f2b(r8[k]);
        ((ushort8_t*)outb)[(size_t)n * 32 + p * 16 + cl16] = o;
      } else {
        float4 w0 = make_float4(r8[0], r8[1], r8[2], r8[3]);
        float4 w1 = make_float4(r8[4], r8[5], r8[6], r8[7]);
        ((float4*)outf)[(size_t)n * 64 + (cbase >> 2)] = w0;
        ((float4*)outf)[(size_t)n * 64 + (cbase >> 2) + 1] = w1;
      }
#pragma unroll
      for (int k = 0; k < 8; k++) {
        lds_v[wv][cbase + k] = r8[k];
        lds_q[wv][cbase + k] = r8[k] * r8[k];
      }
    }
  }
  __syncthreads();
  // ---- BN partials: 256 threads, channel t, 2 atomics into 32 buckets
  int t = threadIdx.x;
  float sv = lds_v[0][t] + lds_v[1][t] + lds_v[2][t] + lds_v[3][t];
  float sq = lds_q[0][t] + lds_q[1][t] + lds_q[2][t] + lds_q[3][t];
  float* pv = bkt + (blockIdx.x & 31) * 512;
  atomicAdd(pv + t, sv);
  atomicAdd(pv + 256 + t, sq);
}

// ---------------------------------------------------------------- final BN (red+apply fused)
__global__ __launch_bounds__(256) void k_bnout(const float* __restrict__ bkt,
                                               const float* __restrict__ g,
                                               const float* __restrict__ be,
                                               const float* __restrict__ x,
                                               float* __restrict__ y) {
  __shared__ float2 p[256];
  int t = threadIdx.x;
  float s = 0.f, q = 0.f;
#pragma unroll 8
  for (int b = 0; b < 32; b++) {
    s += bkt[b * 512 + t];
    q += bkt[b * 512 + 256 + t];
  }
  float m = s * (1.0f / NN);
  float v = q * (1.0f / NN) - m * m;
  float rs = rsqrtf(v + 1e-5f) * g[t];
  p[t] = make_float2(rs, be[t] - m * rs);
  __syncthreads();
  int i = blockIdx.x * 256 + t;  // float4 index over NN*64
  int c = i & 63;
  float2 p0 = p[c * 4], p1 = p[c * 4 + 1], p2 = p[c * 4 + 2], p3 = p[c * 4 + 3];
  float4 xv = ((const float4*)x)[i];
  float4 r;
  r.x = fmaf(xv.x, p0.x, p0.y);
  r.y = fmaf(xv.y, p1.x, p1.y);
  r.z = fmaf(xv.z, p2.x, p2.y);
  r.w = fmaf(xv.w, p3.x, p3.y);
  ((float4*)y)[i] = r;
}

// ---------------------------------------------------------------- launch
extern "C" void kernel_launch(void* const* d_in, const int* in_sizes, int n_in,
                              void* d_out, int out_size, void* d_ws, size_t ws_size,
                              hipStream_t stream) {
  const float* x   = (const float*)d_in[0];
  const int*   ei  = (const int*)d_in[1];
  const float* W0  = (const float*)d_in[2];
  const float* as0 = (const float*)d_in[3];
  const float* ad0 = (const float*)d_in[4];
  const float* b0  = (const float*)d_in[5];
  const float* g0  = (const float*)d_in[6];
  const float* be0 = (const float*)d_in[7];
  const float* W1  = (const float*)d_in[8];
  const float* as1 = (const float*)d_in[9];
  const float* ad1 = (const float*)d_in[10];
  const float* b1  = (const float*)d_in[11];
  const float* g1  = (const float*)d_in[12];
  const float* be1 = (const float*)d_in[13];
  const float* W2  = (const float*)d_in[14];
  const float* as2 = (const float*)d_in[15];
  const float* ad2 = (const float*)d_in[16];
  const float* b2  = (const float*)d_in[17];
  const float* g2  = (const float*)d_in[18];
  const float* be2 = (const float*)d_in[19];
  float* out = (float*)d_out;

  // workspace layout
  u16* hb   = (u16*)d_ws;                   // HBROWS*256 bf16 (padded rows)
  u16* abf  = hb + (size_t)HBROWS * 256;    // NN*128 bf16 (layer-0 input)
  u16* ab16 = abf + (size_t)NN * 128;       // NN*256 bf16 (inter-layer, pre-BN)
  u16* Wt0  = ab16 + (size_t)NN * 256;      // 256*128
  u16* Wt1  = Wt0 + 256 * 128;              // 256*256
  u16* Wt2  = Wt1 + 256 * 256;              // 256*256
  float* asrc = (float*)(Wt2 + 256 * 256);  // NN*4
  float* adst = asrc + NN * 4;              // NN*4
  float* aggf = adst + NN * 4;              // NN*256 f32 (final layer only)
  float* bkt  = aggf + (size_t)NN * 256;    // 3 * 32 * 512
  int* cnt    = (int*)(bkt + 3 * 32 * 512); // NN (adjacent -> one memset)
  int* rowst  = cnt + NN;                   // NN+1
  int* cursor = rowst + NN + 1;             // NN
  int* csrc   = cursor + NN;                // ET

  // ---- one memset covers buckets + cnt
  hipMemsetAsync(bkt, 0, (3 * 32 * 512 + NN) * sizeof(float), stream);
  k_castcnt<<<1290, 256, 0, stream>>>(ei, cnt, x, W0, W1, W2, abf, Wt0, Wt1, Wt2);
  k_scan<<<1, 1024, 0, stream>>>(cnt, rowst, cursor, csrc);

  // ---- layer 0 (no input BN; CSR edge-fill rides along as extra blocks)
  k_gemm<128, 0, 1><<<314 + 1250, 256, 0, stream>>>(
      abf, nullptr, nullptr, nullptr, Wt0, as0, ad0, hb, asrc, adst, 4,
      ei, cursor, csrc);
  k_softagg<4, 1><<<NN / 4, 256, 0, stream>>>(rowst, csrc, asrc, adst, hb, b0,
                                              nullptr, ab16, bkt);

  // ---- layer 1 (BN0+ReLU fused into A-load)
  k_gemm<256, 1, 0><<<314, 256, 0, stream>>>(
      ab16, bkt, g0, be0, Wt1, as1, ad1, hb, asrc, adst, 4,
      nullptr, nullptr, nullptr);
  k_softagg<4, 1><<<NN / 4, 256, 0, stream>>>(rowst, csrc, asrc, adst, hb, b1,
                                              nullptr, ab16, bkt + 32 * 512);

  // ---- layer 2 (BN1+ReLU fused; H=1 slot partials)
  k_gemm<256, 1, 0><<<314, 256, 0, stream>>>(
      ab16, bkt + 32 * 512, g1, be1, Wt2, as2, ad2, hb, asrc, adst, 1,
      nullptr, nullptr, nullptr);
  k_softagg<1, 0><<<NN / 4, 256, 0, stream>>>(rowst, csrc, asrc, adst, hb, b2,
                                              aggf, nullptr, bkt + 2 * 32 * 512);

  // ---- final BN (reduce + apply fused) -> out (f32)
  k_bnout<<<NN / 4, 256, 0, stream>>>(bkt + 2 * 32 * 512, g2, be2, aggf, out);
}

// Round 12
// 281.668 us; speedup vs baseline: 1.0321x; 1.0321x over previous
//
#include <hip/hip_runtime.h>
#include <math.h>

#define NN 10000
#define EE 320000
#define ET (EE + NN)   // 330000 edges incl. self-loops
#define HBROWS 10048   // hb padded to grid rows (157*64)

typedef __attribute__((ext_vector_type(8))) short short8;          // 8 x bf16
typedef __attribute__((ext_vector_type(8))) unsigned short ushort8_t;
typedef __attribute__((ext_vector_type(4))) float f32x4;
typedef unsigned short u16;

static __device__ __forceinline__ float b2f(u16 u) {
  return __uint_as_float(((unsigned)u) << 16);
}
static __device__ __forceinline__ u16 f2b(float f) {
  unsigned u = __float_as_uint(f);
  unsigned r = (u + 0x7FFFu + ((u >> 16) & 1u)) >> 16;  // RNE
  return (u16)r;
}

// ---------------------------------------------------------------- casts + degree count
// blocks [0,1250): degree-count atomic + x->bf16 cast (same index range)
// blocks [1250,1290): one 64x64 W-transpose tile each (LDS, coalesced both sides)
__global__ __launch_bounds__(256) void k_castcnt(
    const int* __restrict__ ei, int* __restrict__ cnt, const float* __restrict__ x,
    const float* __restrict__ W0, const float* __restrict__ W1,
    const float* __restrict__ W2, u16* __restrict__ abf, u16* __restrict__ Wt0,
    u16* __restrict__ Wt1, u16* __restrict__ Wt2) {
  int b = blockIdx.x, tid = threadIdx.x;
  if (b < 1250) {
    int e = b * 256 + tid;  // < 320000 == EE == NN*128/4
    atomicAdd(&cnt[ei[EE + e]], 1);
    float4 f = ((const float4*)x)[e];
    ushort4 o;
    o.x = f2b(f.x); o.y = f2b(f.y); o.z = f2b(f.z); o.w = f2b(f.w);
    ((ushort4*)abf)[e] = o;
    return;
  }
  __shared__ float tile[64][65];
  int wt = b - 1250;
  const float* W; u16* Wt; int K, kt, nt_;
  if (wt < 8)       { W = W0; Wt = Wt0; K = 128; kt = wt & 1; nt_ = wt >> 1; }
  else if (wt < 24) { W = W1; Wt = Wt1; K = 256; int u = wt - 8;  kt = u & 3; nt_ = u >> 2; }
  else              { W = W2; Wt = Wt2; K = 256; int u = wt - 24; kt = u & 3; nt_ = u >> 2; }
  int k0 = kt * 64, n0 = nt_ * 64;
  int tx = tid & 63, ty = tid >> 6;
#pragma unroll
  for (int it = 0; it < 16; it++) {
    int row = it * 4 + ty;
    tile[row][tx] = W[(size_t)(k0 + row) * 256 + n0 + tx];
  }
  __syncthreads();
#pragma unroll
  for (int it = 0; it < 16; it++) {
    int row = it * 4 + ty;
    Wt[(size_t)(n0 + row) * K + k0 + tx] = f2b(tile[tx][row]);
  }
}

// ---------------------------------------------------------------- CSR scan
__global__ __launch_bounds__(1024) void k_scan(const int* __restrict__ cnt,
                                               int* __restrict__ rowst,
                                               int* __restrict__ cursor,
                                               int* __restrict__ csrc) {
  __shared__ int ws[16];
  int tid = threadIdx.x, lane = tid & 63, wv = tid >> 6;
  int base = tid * 10;
  int v[10];
  int tot = 0;
#pragma unroll
  for (int i = 0; i < 10; i++) {
    int idx = base + i;
    v[i] = (idx < NN) ? (cnt[idx] + 1) : 0;
    tot += v[i];
  }
  int sc = tot;
#pragma unroll
  for (int off = 1; off < 64; off <<= 1) {
    int t = __shfl_up(sc, off);
    if (lane >= off) sc += t;
  }
  if (lane == 63) ws[wv] = sc;
  __syncthreads();
  if (wv == 0 && lane < 16) {
    int val = ws[lane];
    int s = val;
#pragma unroll
    for (int off = 1; off < 16; off <<= 1) {
      int t = __shfl_up(s, off);
      if (lane >= off) s += t;
    }
    ws[lane] = s - val;
  }
  __syncthreads();
  int run = ws[wv] + sc - tot;
#pragma unroll
  for (int i = 0; i < 10; i++) {
    int idx = base + i;
    if (idx < NN) {
      rowst[idx] = run;
      csrc[run] = idx;        // self-loop at slot 0
      cursor[idx] = run + 1;
      run += v[i];
    }
  }
  if (tid == 1023) rowst[NN] = run;
}

// ---------------------------------------------------------------- MFMA GEMM (+BN in, +dots, +opt fill)
// gemm units: b in [0,314): gx=b>>1, gy=b&1. Block=64rx128c, 4 waves.
// FILL=1: blocks [314,314+1250) do the CSR edge-fill (overlapped work).
// BN=1: A bf16 pre-BN; scale/shift from buckets applied + ReLU before MFMA.
// C-store: per-wave LDS transpose -> 4x coalesced 16B stores per lane.
// Dots: H=4 slot=head; H=1 slots {2y}=col-half partial, {2y+1}=0.
template <int KK, int BN, int FILL>
__global__ __launch_bounds__(256) void k_gemm(
    const u16* __restrict__ A, const float* __restrict__ bkt,
    const float* __restrict__ gam, const float* __restrict__ bet,
    const u16* __restrict__ Wt, const float* __restrict__ as,
    const float* __restrict__ ad, u16* __restrict__ hb,
    float* __restrict__ asrc, float* __restrict__ adst, int H,
    const int* __restrict__ ei, int* __restrict__ cursor, int* __restrict__ csrc) {
  if (FILL && blockIdx.x >= 314) {
    int e = (blockIdx.x - 314) * 256 + threadIdx.x;
    if (e < EE) {
      int d = ei[EE + e];
      int pos = atomicAdd(&cursor[d], 1);
      csrc[pos] = ei[e];
    }
    return;
  }
  __shared__ float2 bnp[256];
  __shared__ u16 lds_c[4][16][136];
  if (BN) {
    int t = threadIdx.x;
    float s = 0.f, q = 0.f;
#pragma unroll 8
    for (int b = 0; b < 32; b++) {
      s += bkt[b * 512 + t];
      q += bkt[b * 512 + 256 + t];
    }
    float m = s * (1.0f / NN);
    float v = q * (1.0f / NN) - m * m;
    float rs = rsqrtf(v + 1e-5f) * gam[t];
    bnp[t] = make_float2(rs, bet[t] - m * rs);
    __syncthreads();
  }
  int wv = threadIdx.x >> 6, lane = threadIdx.x & 63;
  int gx = blockIdx.x >> 1, gy = blockIdx.x & 1;
  int row0 = gx * 64 + wv * 16;
  int col0 = gy * 128;
  int r = lane & 15, g = lane >> 4;
  f32x4 acc[8];
#pragma unroll
  for (int nt = 0; nt < 8; nt++) acc[nt] = (f32x4){0.f, 0.f, 0.f, 0.f};

  int ar = row0 + r;
  if (ar > NN - 1) ar = NN - 1;  // clamp A reads

#pragma unroll
  for (int ks = 0; ks < KK / 32; ks++) {
    short8 af;
    short8 raw = *(const short8*)(A + (size_t)ar * KK + ks * 32 + g * 8);
    if (BN == 0) {
      af = raw;
    } else {
      int c0 = ks * 32 + g * 8;
#pragma unroll
      for (int j = 0; j < 8; j++) {
        float2 p = bnp[c0 + j];
        float t = fmaxf(fmaf(b2f((u16)raw[j]), p.x, p.y), 0.f);
        af[j] = (short)f2b(t);
      }
    }
#pragma unroll
    for (int nt = 0; nt < 8; nt++) {
      short8 bf = *(const short8*)(Wt + (size_t)(col0 + nt * 16 + r) * KK + ks * 32 + g * 8);
      acc[nt] = __builtin_amdgcn_mfma_f32_16x16x32_bf16(af, bf, acc[nt], 0, 0, 0);
    }
  }
  // ---- C-store: wave-local LDS transpose -> coalesced ushort8 stores
  // C/D: col = lane&15, row = (lane>>4)*4 + reg   [m89/m91]
#pragma unroll
  for (int nt = 0; nt < 8; nt++)
#pragma unroll
    for (int q = 0; q < 4; q++)
      lds_c[wv][g * 4 + q][nt * 16 + r] = f2b(acc[nt][q]);
#pragma unroll
  for (int j = 0; j < 4; j++) {
    int c = j * 64 + lane;
    int row = c >> 4, off = (c & 15) * 8;
    ushort8_t vv = *(const ushort8_t*)&lds_c[wv][row][off];
    *(ushort8_t*)&hb[(size_t)(row0 + row) * 256 + col0 + off] = vv;
  }
  // ---- attention-dot epilogue (f32 acc)
  float asv[8], adv[8];
#pragma unroll
  for (int nt = 0; nt < 8; nt++) {
    asv[nt] = as[col0 + nt * 16 + r];
    adv[nt] = ad[col0 + nt * 16 + r];
  }
#pragma unroll
  for (int q = 0; q < 4; q++) {
    int row = row0 + g * 4 + q;
    if (H == 4) {
#pragma unroll
      for (int hh = 0; hh < 2; hh++) {
        float ps = 0.f, pd = 0.f;
#pragma unroll
        for (int k = 0; k < 4; k++) {
          ps = fmaf(acc[hh * 4 + k][q], asv[hh * 4 + k], ps);
          pd = fmaf(acc[hh * 4 + k][q], adv[hh * 4 + k], pd);
        }
#pragma unroll
        for (int off = 1; off < 16; off <<= 1) {
          ps += __shfl_xor(ps, off);
          pd += __shfl_xor(pd, off);
        }
        if (r == 0 && row < NN) {
          int slot = 2 * gy + hh;
          asrc[row * 4 + slot] = ps;
          adst[row * 4 + slot] = pd;
        }
      }
    } else {
      float ps = 0.f, pd = 0.f;
#pragma unroll
      for (int nt = 0; nt < 8; nt++) {
        ps = fmaf(acc[nt][q], asv[nt], ps);
        pd = fmaf(acc[nt][q], adv[nt], pd);
      }
#pragma unroll
      for (int off = 1; off < 16; off <<= 1) {
        ps += __shfl_xor(ps, off);
        pd += __shfl_xor(pd, off);
      }
      if (r == 0 && row < NN) {
        int slot = 2 * gy;
        asrc[row * 4 + slot] = ps;
        asrc[row * 4 + slot + 1] = 0.f;
        adst[row * 4 + slot] = pd;
        adst[row * 4 + slot + 1] = 0.f;
      }
    }
  }
}

// ---------------------------------------------------------------- fused softmax+agg (+BN partials)
// Phase A: wave softmax (lane-per-edge, ids+weights to LDS, zero-pad to x16).
// Phase B: 16-edge iterations; lane = (half = edge parity, cl = channel oct);
// ushort8 (16B) gathers -> 2 rows per wave-instr; parity combine via shfl_xor(32).
template <int H, int BOUT>
__global__ __launch_bounds__(256) void k_softagg(
    const int* __restrict__ rowst, const int* __restrict__ csrc,
    const float* __restrict__ asrc, const float* __restrict__ adst,
    const u16* __restrict__ hb, const float* __restrict__ bias,
    float* __restrict__ outf, u16* __restrict__ outb, float* __restrict__ bkt) {
  __shared__ int lds_s[4][128];
  __shared__ float lds_w[4][128][H];
  __shared__ float lds_v[4][256];
  __shared__ float lds_q[4][256];
  int wv = threadIdx.x >> 6, lane = threadIdx.x & 63;
  int n = blockIdx.x * 4 + wv;  // NN % 4 == 0
  int rs = rowst[n], re = rowst[n + 1];

  float ad[H];
  {
    float4 t = ((const float4*)adst)[n];
    if (H == 4) { ad[0] = t.x; ad[1] = t.y; ad[2] = t.z; ad[3] = t.w; }
    else ad[0] = t.x + t.y + t.z + t.w;
  }
  float mx[H], sm[H];
#pragma unroll
  for (int h = 0; h < H; h++) { mx[h] = -1e30f; sm[h] = 0.f; }

  int e0 = rs + lane, e1 = e0 + 64;
  bool h0 = e0 < re, h1 = e1 < re;
  float a0[H], a1[H];

  if (h0) {
    int s = csrc[e0];
    lds_s[wv][lane] = s;
    float4 t = ((const float4*)asrc)[s];
    if (H == 4) { a0[0] = t.x; a0[1] = t.y; a0[2] = t.z; a0[3] = t.w; }
    else a0[0] = t.x + t.y + t.z + t.w;
#pragma unroll
    for (int h = 0; h < H; h++) {
      float v = a0[h] + ad[h];
      v = v > 0.f ? v : 0.2f * v;
      a0[h] = v;
      mx[h] = fmaxf(mx[h], v);
    }
  }
  if (h1) {
    int s = csrc[e1];
    lds_s[wv][64 + lane] = s;
    float4 t = ((const float4*)asrc)[s];
    if (H == 4) { a1[0] = t.x; a1[1] = t.y; a1[2] = t.z; a1[3] = t.w; }
    else a1[0] = t.x + t.y + t.z + t.w;
#pragma unroll
    for (int h = 0; h < H; h++) {
      float v = a1[h] + ad[h];
      v = v > 0.f ? v : 0.2f * v;
      a1[h] = v;
      mx[h] = fmaxf(mx[h], v);
    }
  }
  for (int e = rs + 128 + lane; e < re; e += 64) {  // cold (deg>128): max only
    int s = csrc[e];
    float4 t = ((const float4*)asrc)[s];
    float a[H];
    if (H == 4) { a[0] = t.x; a[1] = t.y; a[2] = t.z; a[3] = t.w; }
    else a[0] = t.x + t.y + t.z + t.w;
#pragma unroll
    for (int h = 0; h < H; h++) {
      float v = a[h] + ad[h];
      v = v > 0.f ? v : 0.2f * v;
      mx[h] = fmaxf(mx[h], v);
    }
  }
#pragma unroll
  for (int off = 32; off; off >>= 1)
#pragma unroll
    for (int h = 0; h < H; h++) mx[h] = fmaxf(mx[h], __shfl_xor(mx[h], off));

  if (h0) {
#pragma unroll
    for (int h = 0; h < H; h++) {
      a0[h] = __expf(a0[h] - mx[h]);
      sm[h] += a0[h];
      lds_w[wv][lane][h] = a0[h];
    }
  }
  if (h1) {
#pragma unroll
    for (int h = 0; h < H; h++) {
      a1[h] = __expf(a1[h] - mx[h]);
      sm[h] += a1[h];
      lds_w[wv][64 + lane][h] = a1[h];
    }
  }
  for (int e = rs + 128 + lane; e < re; e += 64) {  // cold: exp+sum
    int s = csrc[e];
    float4 t = ((const float4*)asrc)[s];
    float a[H];
    if (H == 4) { a[0] = t.x; a[1] = t.y; a[2] = t.z; a[3] = t.w; }
    else a[0] = t.x + t.y + t.z + t.w;
#pragma unroll
    for (int h = 0; h < H; h++) {
      float v = a[h] + ad[h];
      v = v > 0.f ? v : 0.2f * v;
      sm[h] += __expf(v - mx[h]);
    }
  }
#pragma unroll
  for (int off = 32; off; off >>= 1)
#pragma unroll
    for (int h = 0; h < H; h++) sm[h] += __shfl_xor(sm[h], off);

  float inv[H];
#pragma unroll
  for (int h = 0; h < H; h++) inv[h] = 1.0f / (sm[h] + 1e-16f);

  // ---- zero-pad LDS slots up to a multiple of 16
  int m = re - rs;
  if (m > 128) m = 128;
  int mp = (m + 15) & ~15;
  for (int p = m + lane; p < mp; p += 64) {
    lds_s[wv][p] = n;  // valid row; weight 0
#pragma unroll
    for (int h = 0; h < H; h++) lds_w[wv][p][h] = 0.f;
  }

  // ---- phase B: aggregation (lane = parity x channel-oct), 16 edges/iter
  int cl = lane & 31, half = lane >> 5;
  int hd8 = (H == 4) ? (cl >> 3) : 0;
  float invh = (H == 4) ? (hd8 == 0 ? inv[0] : hd8 == 1 ? inv[1] : hd8 == 2 ? inv[2] : inv[3])
                        : inv[0];
  float mh = (H == 4) ? (hd8 == 0 ? mx[0] : hd8 == 1 ? mx[1] : hd8 == 2 ? mx[2] : mx[3])
                      : mx[0];
  float adh = (H == 4) ? (hd8 == 0 ? ad[0] : hd8 == 1 ? ad[1] : hd8 == 2 ? ad[2] : ad[3])
                       : ad[0];
  const ushort8_t* h8 = (const ushort8_t*)hb;
  float acc[8] = {0.f, 0.f, 0.f, 0.f, 0.f, 0.f, 0.f, 0.f};
  for (int e = 0; e < mp; e += 16) {
    int ss[8];
    float ww[8];
    ushort8_t vv[8];
#pragma unroll
    for (int j = 0; j < 8; j++) ss[j] = lds_s[wv][e + 2 * j + half];
#pragma unroll
    for (int j = 0; j < 8; j++) ww[j] = lds_w[wv][e + 2 * j + half][hd8];
#pragma unroll
    for (int j = 0; j < 8; j++) vv[j] = h8[(size_t)ss[j] * 32 + cl];
#pragma unroll
    for (int j = 0; j < 8; j++)
#pragma unroll
      for (int k = 0; k < 8; k++) acc[k] = fmaf(ww[j], b2f((u16)vv[j][k]), acc[k]);
  }
  for (int ee = rs + 128 + half; ee < re; ee += 2) {  // cold: recompute w
    int s = csrc[ee];
    float4 t = ((const float4*)asrc)[s];
    float av = (H == 4) ? (hd8 == 0 ? t.x : hd8 == 1 ? t.y : hd8 == 2 ? t.z : t.w)
                        : (t.x + t.y + t.z + t.w);
    float vv2 = av + adh;
    vv2 = vv2 > 0.f ? vv2 : 0.2f * vv2;
    float w = __expf(vv2 - mh);
    ushort8_t v = h8[(size_t)s * 32 + cl];
#pragma unroll
    for (int k = 0; k < 8; k++) acc[k] = fmaf(w, b2f((u16)v[k]), acc[k]);
  }
#pragma unroll
  for (int k = 0; k < 8; k++) acc[k] += __shfl_xor(acc[k], 32);

  float4 ba = ((const float4*)bias)[cl * 2];
  float4 bb = ((const float4*)bias)[cl * 2 + 1];
  float r8[8];
  r8[0] = acc[0] * invh + ba.x; r8[1] = acc[1] * invh + ba.y;
  r8[2] = acc[2] * invh + ba.z; r8[3] = acc[3] * invh + ba.w;
  r8[4] = acc[4] * invh + bb.x; r8[5] = acc[5] * invh + bb.y;
  r8[6] = acc[6] * invh + bb.z; r8[7] = acc[7] * invh + bb.w;

  if (half == 0) {
    if (BOUT) {
      ushort8_t o;
#pragma unroll
      for (int k = 0; k < 8; k++) o[k] = f2b(r8[k]);
      ((ushort8_t*)outb)[(size_t)n * 32 + cl] = o;
    } else {
      float4 w0 = make_float4(r8[0], r8[1], r8[2], r8[3]);
      float4 w1 = make_float4(r8[4], r8[5], r8[6], r8[7]);
      ((float4*)outf)[(size_t)n * 64 + cl * 2] = w0;
      ((float4*)outf)[(size_t)n * 64 + cl * 2 + 1] = w1;
    }
#pragma unroll
    for (int k = 0; k < 8; k++) {
      lds_v[wv][cl * 8 + k] = r8[k];
      lds_q[wv][cl * 8 + k] = r8[k] * r8[k];
    }
  }
  __syncthreads();
  // ---- BN partials: 256 threads, channel t, 2 atomics into 32 buckets
  int t = threadIdx.x;
  float sv = lds_v[0][t] + lds_v[1][t] + lds_v[2][t] + lds_v[3][t];
  float sq = lds_q[0][t] + lds_q[1][t] + lds_q[2][t] + lds_q[3][t];
  float* pv = bkt + (blockIdx.x & 31) * 512;
  atomicAdd(pv + t, sv);
  atomicAdd(pv + 256 + t, sq);
}

// ---------------------------------------------------------------- final BN (red+apply fused)
__global__ __launch_bounds__(256) void k_bnout(const float* __restrict__ bkt,
                                               const float* __restrict__ g,
                                               const float* __restrict__ be,
                                               const float* __restrict__ x,
                                               float* __restrict__ y) {
  __shared__ float2 p[256];
  int t = threadIdx.x;
  float s = 0.f, q = 0.f;
#pragma unroll 8
  for (int b = 0; b < 32; b++) {
    s += bkt[b * 512 + t];
    q += bkt[b * 512 + 256 + t];
  }
  float m = s * (1.0f / NN);
  float v = q * (1.0f / NN) - m * m;
  float rs = rsqrtf(v + 1e-5f) * g[t];
  p[t] = make_float2(rs, be[t] - m * rs);
  __syncthreads();
  int i = blockIdx.x * 256 + t;  // float4 index over NN*64
  int c = i & 63;
  float2 p0 = p[c * 4], p1 = p[c * 4 + 1], p2 = p[c * 4 + 2], p3 = p[c * 4 + 3];
  float4 xv = ((const float4*)x)[i];
  float4 r;
  r.x = fmaf(xv.x, p0.x, p0.y);
  r.y = fmaf(xv.y, p1.x, p1.y);
  r.z = fmaf(xv.z, p2.x, p2.y);
  r.w = fmaf(xv.w, p3.x, p3.y);
  ((float4*)y)[i] = r;
}

// ---------------------------------------------------------------- launch
// Deterministic 10-dispatch sequence (R8 structure, measured 282 us).
// NO cooperative launch, NO runtime branching — graph-capture-stable.
extern "C" void kernel_launch(void* const* d_in, const int* in_sizes, int n_in,
                              void* d_out, int out_size, void* d_ws, size_t ws_size,
                              hipStream_t stream) {
  const float* x   = (const float*)d_in[0];
  const int*   ei  = (const int*)d_in[1];
  const float* W0  = (const float*)d_in[2];
  const float* as0 = (const float*)d_in[3];
  const float* ad0 = (const float*)d_in[4];
  const float* b0  = (const float*)d_in[5];
  const float* g0  = (const float*)d_in[6];
  const float* be0 = (const float*)d_in[7];
  const float* W1  = (const float*)d_in[8];
  const float* as1 = (const float*)d_in[9];
  const float* ad1 = (const float*)d_in[10];
  const float* b1  = (const float*)d_in[11];
  const float* g1  = (const float*)d_in[12];
  const float* be1 = (const float*)d_in[13];
  const float* W2  = (const float*)d_in[14];
  const float* as2 = (const float*)d_in[15];
  const float* ad2 = (const float*)d_in[16];
  const float* b2  = (const float*)d_in[17];
  const float* g2  = (const float*)d_in[18];
  const float* be2 = (const float*)d_in[19];
  float* out = (float*)d_out;

  // workspace layout (same as R8)
  u16* hb   = (u16*)d_ws;                   // HBROWS*256 bf16 (padded rows)
  u16* abf  = hb + (size_t)HBROWS * 256;    // NN*128 bf16 (layer-0 input)
  u16* ab16 = abf + (size_t)NN * 128;       // NN*256 bf16 (inter-layer, pre-BN)
  u16* Wt0  = ab16 + (size_t)NN * 256;      // 256*128
  u16* Wt1  = Wt0 + 256 * 128;              // 256*256
  u16* Wt2  = Wt1 + 256 * 256;              // 256*256
  float* asrc = (float*)(Wt2 + 256 * 256);  // NN*4
  float* adst = asrc + NN * 4;              // NN*4
  float* aggf = adst + NN * 4;              // NN*256 f32 (final layer only)
  float* bkt  = aggf + (size_t)NN * 256;    // 3 * 32 * 512
  int* cnt    = (int*)(bkt + 3 * 32 * 512); // NN (adjacent -> one memset)
  int* rowst  = cnt + NN;                   // NN+1
  int* cursor = rowst + NN + 1;             // NN
  int* csrc   = cursor + NN;                // ET

  // ---- one memset covers buckets + cnt
  hipMemsetAsync(bkt, 0, (3 * 32 * 512 + NN) * sizeof(float), stream);
  k_castcnt<<<1290, 256, 0, stream>>>(ei, cnt, x, W0, W1, W2, abf, Wt0, Wt1, Wt2);
  k_scan<<<1, 1024, 0, stream>>>(cnt, rowst, cursor, csrc);

  // ---- layer 0 (no input BN; CSR edge-fill rides along as extra blocks)
  k_gemm<128, 0, 1><<<314 + 1250, 256, 0, stream>>>(
      abf, nullptr, nullptr, nullptr, Wt0, as0, ad0, hb, asrc, adst, 4,
      ei, cursor, csrc);
  k_softagg<4, 1><<<NN / 4, 256, 0, stream>>>(rowst, csrc, asrc, adst, hb, b0,
                                              nullptr, ab16, bkt);

  // ---- layer 1 (BN0+ReLU fused into A-load)
  k_gemm<256, 1, 0><<<314, 256, 0, stream>>>(
      ab16, bkt, g0, be0, Wt1, as1, ad1, hb, asrc, adst, 4,
      nullptr, nullptr, nullptr);
  k_softagg<4, 1><<<NN / 4, 256, 0, stream>>>(rowst, csrc, asrc, adst, hb, b1,
                                              nullptr, ab16, bkt + 32 * 512);

  // ---- layer 2 (BN1+ReLU fused; H=1 slot partials)
  k_gemm<256, 1, 0><<<314, 256, 0, stream>>>(
      ab16, bkt + 32 * 512, g1, be1, Wt2, as2, ad2, hb, asrc, adst, 1,
      nullptr, nullptr, nullptr);
  k_softagg<1, 0><<<NN / 4, 256, 0, stream>>>(rowst, csrc, asrc, adst, hb, b2,
                                              aggf, nullptr, bkt + 2 * 32 * 512);

  // ---- final BN (reduce + apply fused) -> out (f32)
  k_bnout<<<NN / 4, 256, 0, stream>>>(bkt + 2 * 32 * 512, g2, be2, aggf, out);
}